// Round 1
// 668.808 us; speedup vs baseline: 1.1299x; 1.1299x over previous
//
#include <hip/hip_runtime.h>

// Problem constants (static in the reference)
#define NN 1024
#define MM 64
#define BB 8
#define EE 63456   // sum_i min(i,64) = 2016 + 960*64

// ws float layout (fp32 scratch for collapsed weights)
#define WS_WN    0        // Wn_eff  192*64
#define WS_WE    12288    // We_eff  128*64
#define WS_BN    20480    // bn_eff  64
#define WS_BE    20544    // be_eff  64
#define WS_TOTAL 20608    // floats (~82 KB)

// Kernel A: collapse the inner linear pairs (no inner ReLU in the reference!)
__global__ void eff_weights_kernel(
    const float* __restrict__ Wn1, const float* __restrict__ bn1,
    const float* __restrict__ Wn2, const float* __restrict__ bn2,
    const float* __restrict__ We1, const float* __restrict__ be1,
    const float* __restrict__ We2, const float* __restrict__ be2,
    float* __restrict__ ws)
{
    int idx = blockIdx.x * 256 + threadIdx.x;
    if (idx < 12288) {                       // Wn_eff (192x64)
        int r = idx >> 6, j = idx & 63;
        float acc = 0.f;
        for (int t = 0; t < 128; ++t) acc += Wn1[r * 128 + t] * Wn2[t * 64 + j];
        ws[WS_WN + idx] = acc;
    } else if (idx < 20480) {                // We_eff (128x64)
        int k = idx - 12288; int r = k >> 6, j = k & 63;
        float acc = 0.f;
        for (int t = 0; t < 128; ++t) acc += We1[r * 128 + t] * We2[t * 64 + j];
        ws[idx] = acc;
    } else if (idx < 20544) {                // bn_eff
        int j = idx - 20480;
        float acc = bn2[j];
        for (int t = 0; t < 128; ++t) acc += bn1[t] * Wn2[t * 64 + j];
        ws[idx] = acc;
    } else if (idx < WS_TOTAL) {             // be_eff
        int j = idx - 20544;
        float acc = be2[j];
        for (int t = 0; t < 128; ++t) acc += be1[t] * We2[t * 64 + j];
        ws[idx] = acc;
    }
}

// Kernel B: one block per (batch b, node i).
// Thread tile: 4 features (fg) x 4 edges (eg). Data LDS reads are 16-lane
// broadcasts (4 distinct rows/instr); weights are float4 from L1/L2.
// Prefix-mean done post-GEMM in registers via linearity (no serial scan wave).
__global__ __launch_bounds__(256, 3)
void main_kernel(const float* __restrict__ nodes,
                 const float* __restrict__ edges,
                 const float* __restrict__ ws,
                 const float* __restrict__ Wnf,   // W_nodes (128x64)
                 const float* __restrict__ Wef,   // W_edges (128x64)
                 const float* __restrict__ bias,  // bias_edges (64) — used for BOTH outputs (ref does this)
                 float* __restrict__ out)
{
    __shared__ float s_nodes[65 * 64];   // rows 0..w = nodes i-w .. i
    __shared__ float s_edges[64 * 64];   // rows 0..w-1
    __shared__ float s_pair[64 * 64];    // pair_e (rows >= w forced to 0)
    __shared__ float s_red[16 * 64];     // pair_n partials; later z-totals

    const int tid = threadIdx.x;
    const int bx  = blockIdx.x;
    const int b   = bx >> 10;
    const int i   = bx & 1023;
    const int w   = (i < MM) ? i : MM;
    const long ns = (i <= 64) ? ((long)i * (i - 1)) / 2 : 2016L + (long)(i - 64) * 64;

    const float* Wn  = ws + WS_WN;
    const float* We  = ws + WS_WE;
    const float* bnE = ws + WS_BN;
    const float* beE = ws + WS_BE;

    // ---- Phase 1: stage inputs (fp32, contiguous, float4) ----
    {
        const float4* gn = (const float4*)(nodes + ((size_t)b * NN + (i - w)) * 64);
        const int nv = (w + 1) * 16;          // 16 float4 per 64-feature row
        for (int idx = tid; idx < nv; idx += 256)
            ((float4*)s_nodes)[idx] = gn[idx];
        const float4* ge = (const float4*)(edges + ((size_t)b * EE + ns) * 64);
        const int ev = w * 16;
        for (int idx = tid; idx < ev; idx += 256)
            ((float4*)s_edges)[idx] = ge[idx];
    }
    __syncthreads();

    const int fg = tid & 15;     // feature group -> features f0..f0+3
    const int f0 = fg << 2;
    const int eg = tid >> 4;     // edge group -> edges j = eg*4 + m, m=0..3

    // ---- Phase 2: pair_n + pair_e, 4x4 register tile per thread ----
    float accn[4][4], acce[4][4];
    {
        float bn0[4], be0[4];
        {
            float4 t = *(const float4*)&bnE[f0];
            bn0[0] = t.x; bn0[1] = t.y; bn0[2] = t.z; bn0[3] = t.w;
            t = *(const float4*)&beE[f0];
            be0[0] = t.x; be0[1] = t.y; be0[2] = t.z; be0[3] = t.w;
        }
        // dst-node contribution identical for every edge: hoist into the base.
        const float* nrow = &s_nodes[w * 64];
        for (int c = 0; c < 64; c += 4) {
            float4 x  = *(const float4*)&nrow[c];
            float4 w0 = *(const float4*)&Wn[(64 + c) * 64 + f0];
            float4 w1 = *(const float4*)&Wn[(65 + c) * 64 + f0];
            float4 w2 = *(const float4*)&Wn[(66 + c) * 64 + f0];
            float4 w3 = *(const float4*)&Wn[(67 + c) * 64 + f0];
            bn0[0] += x.x * w0.x + x.y * w1.x + x.z * w2.x + x.w * w3.x;
            bn0[1] += x.x * w0.y + x.y * w1.y + x.z * w2.y + x.w * w3.y;
            bn0[2] += x.x * w0.z + x.y * w1.z + x.z * w2.z + x.w * w3.z;
            bn0[3] += x.x * w0.w + x.y * w1.w + x.z * w2.w + x.w * w3.w;
        }
#pragma unroll
        for (int m = 0; m < 4; ++m)
#pragma unroll
            for (int ff = 0; ff < 4; ++ff) { accn[m][ff] = bn0[ff]; acce[m][ff] = be0[ff]; }
    }

    for (int c = 0; c < 64; c += 4) {
        float wns[4][4], wne[4][4], wes[4][4], wee[4][4];   // [channel q][feature ff]
#pragma unroll
        for (int q = 0; q < 4; ++q) {
            float4 t;
            t = *(const float4*)&Wn[(c + q) * 64 + f0];
            wns[q][0] = t.x; wns[q][1] = t.y; wns[q][2] = t.z; wns[q][3] = t.w;
            t = *(const float4*)&Wn[(128 + c + q) * 64 + f0];
            wne[q][0] = t.x; wne[q][1] = t.y; wne[q][2] = t.z; wne[q][3] = t.w;
            t = *(const float4*)&We[(c + q) * 64 + f0];
            wes[q][0] = t.x; wes[q][1] = t.y; wes[q][2] = t.z; wes[q][3] = t.w;
            t = *(const float4*)&We[(64 + c + q) * 64 + f0];
            wee[q][0] = t.x; wee[q][1] = t.y; wee[q][2] = t.z; wee[q][3] = t.w;
        }
#pragma unroll
        for (int m = 0; m < 4; ++m) {
            const int j = (eg << 2) + m;      // dead rows (j>=w) compute garbage, never stored
            float4 xs = *(const float4*)&s_nodes[j * 64 + c];
            float4 xe = *(const float4*)&s_edges[j * 64 + c];
#pragma unroll
            for (int ff = 0; ff < 4; ++ff) {
                accn[m][ff] += xs.x * wns[0][ff] + xs.y * wns[1][ff] + xs.z * wns[2][ff] + xs.w * wns[3][ff]
                             + xe.x * wne[0][ff] + xe.y * wne[1][ff] + xe.z * wne[2][ff] + xe.w * wne[3][ff];
                acce[m][ff] += xs.x * wes[0][ff] + xs.y * wes[1][ff] + xs.z * wes[2][ff] + xs.w * wes[3][ff]
                             + xe.x * wee[0][ff] + xe.y * wee[1][ff] + xe.z * wee[2][ff] + xe.w * wee[3][ff];
            }
        }
    }

    {
        float sn[4] = {0.f, 0.f, 0.f, 0.f};
#pragma unroll
        for (int m = 0; m < 4; ++m) {
            const int j = (eg << 2) + m;
            float4 pe = make_float4(0.f, 0.f, 0.f, 0.f);   // rows >= w forced to zero
            if (j < w) {
                pe.x = fmaxf(acce[m][0], 0.f);
                pe.y = fmaxf(acce[m][1], 0.f);
                pe.z = fmaxf(acce[m][2], 0.f);
                pe.w = fmaxf(acce[m][3], 0.f);
                sn[0] += fmaxf(accn[m][0], 0.f);
                sn[1] += fmaxf(accn[m][1], 0.f);
                sn[2] += fmaxf(accn[m][2], 0.f);
                sn[3] += fmaxf(accn[m][3], 0.f);
            }
            *(float4*)&s_pair[j * 64 + f0] = pe;
        }
        *(float4*)&s_red[eg * 64 + f0] = make_float4(sn[0], sn[1], sn[2], sn[3]);
    }
    __syncthreads();

    // ---- half-reduce s_red 16 rows -> 4 rows (each address's only reader is its writer) ----
    {
        const int c = tid & 63, p = tid >> 6;
        float v = s_red[p * 64 + c] + s_red[(p + 4) * 64 + c]
                + s_red[(p + 8) * 64 + c] + s_red[(p + 12) * 64 + c];
        s_red[p * 64 + c] = v;
    }
    __syncthreads();

    // ---- Phase 3 (wave 0 only, overlapped with everyone's Phase 5 GEMM): out_nodes ----
    if (tid < 64) {
        const int f = tid;
        const float invw = 1.0f / (float)((w > 0) ? w : 1);
        float acc = bias[f];
        const float* nrow = &s_nodes[w * 64];
        for (int c = 0; c < 64; c += 4) {
            float4 a0 = *(const float4*)&s_red[c];
            float4 a1 = *(const float4*)&s_red[64 + c];
            float4 a2 = *(const float4*)&s_red[128 + c];
            float4 a3 = *(const float4*)&s_red[192 + c];
            float4 x  = *(const float4*)&nrow[c];
            float g0 = (a0.x + a1.x + a2.x + a3.x) * invw;
            float g1 = (a0.y + a1.y + a2.y + a3.y) * invw;
            float g2 = (a0.z + a1.z + a2.z + a3.z) * invw;
            float g3 = (a0.w + a1.w + a2.w + a3.w) * invw;
            acc += g0 * Wnf[(c + 0) * 64 + f] + g1 * Wnf[(c + 1) * 64 + f]
                 + g2 * Wnf[(c + 2) * 64 + f] + g3 * Wnf[(c + 3) * 64 + f]
                 + x.x * Wnf[(64 + c) * 64 + f] + x.y * Wnf[(65 + c) * 64 + f]
                 + x.z * Wnf[(66 + c) * 64 + f] + x.w * Wnf[(67 + c) * 64 + f];
        }
        out[((size_t)b * NN + i) * 64 + f] = fmaxf(acc, 0.f);
    }

    // ---- Phase 5: z = pair_e @ Wef[0:64] (to be scanned), ze = edge @ Wef[64:128] ----
    float zz[4][4], ze[4][4];
#pragma unroll
    for (int m = 0; m < 4; ++m)
#pragma unroll
        for (int ff = 0; ff < 4; ++ff) { zz[m][ff] = 0.f; ze[m][ff] = 0.f; }

    for (int c = 0; c < 64; c += 4) {
        float w1[4][4], w2[4][4];
#pragma unroll
        for (int q = 0; q < 4; ++q) {
            float4 t;
            t = *(const float4*)&Wef[(c + q) * 64 + f0];
            w1[q][0] = t.x; w1[q][1] = t.y; w1[q][2] = t.z; w1[q][3] = t.w;
            t = *(const float4*)&Wef[(64 + c + q) * 64 + f0];
            w2[q][0] = t.x; w2[q][1] = t.y; w2[q][2] = t.z; w2[q][3] = t.w;
        }
#pragma unroll
        for (int m = 0; m < 4; ++m) {
            const int j = (eg << 2) + m;
            float4 xp = *(const float4*)&s_pair[j * 64 + c];   // zeros for j>=w
            float4 xe = *(const float4*)&s_edges[j * 64 + c];
#pragma unroll
            for (int ff = 0; ff < 4; ++ff) {
                zz[m][ff] += xp.x * w1[0][ff] + xp.y * w1[1][ff] + xp.z * w1[2][ff] + xp.w * w1[3][ff];
                ze[m][ff] += xe.x * w2[0][ff] + xe.y * w2[1][ff] + xe.z * w2[2][ff] + xe.w * w2[3][ff];
            }
        }
    }

    // ---- exclusive prefix of zz over j (registers along m, LDS across eg) ----
    float pref[4][4], tot[4];
#pragma unroll
    for (int ff = 0; ff < 4; ++ff) {
        pref[0][ff] = 0.f;
        pref[1][ff] = zz[0][ff];
        pref[2][ff] = pref[1][ff] + zz[1][ff];
        pref[3][ff] = pref[2][ff] + zz[2][ff];
        tot[ff]     = pref[3][ff] + zz[3][ff];
    }
    __syncthreads();                       // wave0 done reading s_red (phase 3)
    *(float4*)&s_red[eg * 64 + f0] = make_float4(tot[0], tot[1], tot[2], tot[3]);
    __syncthreads();
    float run[4] = {0.f, 0.f, 0.f, 0.f};
    for (int e = 0; e < eg; ++e) {
        float4 t = *(const float4*)&s_red[e * 64 + f0];
        run[0] += t.x; run[1] += t.y; run[2] += t.z; run[3] += t.w;
    }

    // ---- out_edges = relu(prefix_z/max(j,1) + edge@W2 + bias), float4 stores ----
    {
        float4 bv = *(const float4*)&bias[f0];
        float* oute = out + (size_t)BB * NN * 64;  // out_nodes first, then out_edges
#pragma unroll
        for (int m = 0; m < 4; ++m) {
            const int j = (eg << 2) + m;
            if (j < w) {
                const float invj = 1.0f / (float)((j > 0) ? j : 1);
                float4 o;
                o.x = fmaxf((run[0] + pref[m][0]) * invj + ze[m][0] + bv.x, 0.f);
                o.y = fmaxf((run[1] + pref[m][1]) * invj + ze[m][1] + bv.y, 0.f);
                o.z = fmaxf((run[2] + pref[m][2]) * invj + ze[m][2] + bv.z, 0.f);
                o.w = fmaxf((run[3] + pref[m][3]) * invj + ze[m][3] + bv.w, 0.f);
                *(float4*)&oute[((size_t)b * EE + ns + j) * 64 + f0] = o;
            }
        }
    }
}

extern "C" void kernel_launch(void* const* d_in, const int* in_sizes, int n_in,
                              void* d_out, int out_size, void* d_ws, size_t ws_size,
                              hipStream_t stream) {
    const float* nodes = (const float*)d_in[0];
    const float* edges = (const float*)d_in[1];
    const float* Wn1  = (const float*)d_in[2];
    const float* bn1  = (const float*)d_in[3];
    const float* Wn2  = (const float*)d_in[4];
    const float* bn2  = (const float*)d_in[5];
    const float* We1  = (const float*)d_in[6];
    const float* be1  = (const float*)d_in[7];
    const float* We2  = (const float*)d_in[8];
    const float* be2  = (const float*)d_in[9];
    const float* Wnod = (const float*)d_in[10];
    const float* Wedg = (const float*)d_in[11];
    const float* bias = (const float*)d_in[12];
    float* ws = (float*)d_ws;
    float* out = (float*)d_out;

    hipLaunchKernelGGL(eff_weights_kernel, dim3((WS_TOTAL + 255) / 256), dim3(256), 0, stream,
                       Wn1, bn1, Wn2, bn2, We1, be1, We2, be2, ws);
    hipLaunchKernelGGL(main_kernel, dim3(BB * NN), dim3(256), 0, stream,
                       nodes, edges, ws, Wnod, Wedg, bias, out);
}

// Round 2
// 664.623 us; speedup vs baseline: 1.1370x; 1.0063x over previous
//
#include <hip/hip_runtime.h>

// Problem constants (static in the reference)
#define NN 1024
#define MM 64
#define BB 8
#define EE 63456   // sum_i min(i,64) = 2016 + 960*64

// ws float layout (fp32 scratch for collapsed weights)
#define WS_WN    0        // Wn_eff  192*64
#define WS_WE    12288    // We_eff  128*64
#define WS_BN    20480    // bn_eff  64
#define WS_BE    20544    // be_eff  64
#define WS_TOTAL 20608    // floats (~82 KB)

// Kernel A: collapse the inner linear pairs (no inner ReLU in the reference!)
__global__ void eff_weights_kernel(
    const float* __restrict__ Wn1, const float* __restrict__ bn1,
    const float* __restrict__ Wn2, const float* __restrict__ bn2,
    const float* __restrict__ We1, const float* __restrict__ be1,
    const float* __restrict__ We2, const float* __restrict__ be2,
    float* __restrict__ ws)
{
    int idx = blockIdx.x * 256 + threadIdx.x;
    if (idx < 12288) {                       // Wn_eff (192x64)
        int r = idx >> 6, j = idx & 63;
        float acc = 0.f;
        for (int t = 0; t < 128; ++t) acc += Wn1[r * 128 + t] * Wn2[t * 64 + j];
        ws[WS_WN + idx] = acc;
    } else if (idx < 20480) {                // We_eff (128x64)
        int k = idx - 12288; int r = k >> 6, j = k & 63;
        float acc = 0.f;
        for (int t = 0; t < 128; ++t) acc += We1[r * 128 + t] * We2[t * 64 + j];
        ws[idx] = acc;
    } else if (idx < 20544) {                // bn_eff
        int j = idx - 20480;
        float acc = bn2[j];
        for (int t = 0; t < 128; ++t) acc += bn1[t] * Wn2[t * 64 + j];
        ws[idx] = acc;
    } else if (idx < WS_TOTAL) {             // be_eff
        int j = idx - 20544;
        float acc = be2[j];
        for (int t = 0; t < 128; ++t) acc += be1[t] * We2[t * 64 + j];
        ws[idx] = acc;
    }
}

// Kernel B: one block per (batch b, node i).
// Thread tile: 4 features (fg) x 4 edges (eg).
// LDS tiles are XOR-bank-swizzled (float4 col ^ (row>>2)&7) so the 4 distinct
// rows inside each ds_read_b128 hit 4 distinct bank groups (conflict-free).
// s_pair overlays s_nodes rows 0..63 (pair writes j<w only, so dst row w
// survives; garbage rows never reach a stored output) -> 37.1 KB LDS -> 4 blocks/CU.
__global__ __launch_bounds__(256, 4)
void main_kernel(const float* __restrict__ nodes,
                 const float* __restrict__ edges,
                 const float* __restrict__ ws,
                 const float* __restrict__ Wnf,   // W_nodes (128x64)
                 const float* __restrict__ Wef,   // W_edges (128x64)
                 const float* __restrict__ bias,  // bias_edges (64) — used for BOTH outputs (ref does this)
                 float* __restrict__ out)
{
    __shared__ float s_nodes[65 * 64];   // rows 0..w = nodes i-w..i ; rows 0..63 reused as pair_e
    __shared__ float s_edges[64 * 64];   // rows 0..w-1
    __shared__ float s_red[16 * 64];     // pair_n partials; later z-totals

    float4* sn4 = (float4*)s_nodes;
    float4* se4 = (float4*)s_edges;
    float4* sp4 = (float4*)s_nodes;      // pair overlay

    const int tid = threadIdx.x;
    const int bx  = blockIdx.x;
    const int b   = bx >> 10;
    const int i   = bx & 1023;
    const int w   = (i < MM) ? i : MM;
    const long ns = (i <= 64) ? ((long)i * (i - 1)) / 2 : 2016L + (long)(i - 64) * 64;

    const float* Wn  = ws + WS_WN;
    const float* We  = ws + WS_WE;
    const float* bnE = ws + WS_BN;
    const float* beE = ws + WS_BE;

    // ---- Phase 1: stage inputs (coalesced global float4; LDS col XOR-swizzled) ----
    {
        const float4* gn = (const float4*)(nodes + ((size_t)b * NN + (i - w)) * 64);
        const int nv = (w + 1) * 16;          // 16 float4 per 64-feature row
        for (int idx = tid; idx < nv; idx += 256) {
            const int row = idx >> 4, col = idx & 15;
            sn4[(row << 4) | (col ^ ((row >> 2) & 7))] = gn[idx];
        }
        const float4* ge = (const float4*)(edges + ((size_t)b * EE + ns) * 64);
        const int ev = w * 16;
        for (int idx = tid; idx < ev; idx += 256) {
            const int row = idx >> 4, col = idx & 15;
            se4[(row << 4) | (col ^ ((row >> 2) & 7))] = ge[idx];
        }
    }
    __syncthreads();

    const int fg = tid & 15;     // feature group -> features f0..f0+3
    const int f0 = fg << 2;
    const int eg = tid >> 4;     // edge group -> edges j = eg*4 + m, m=0..3
    const int sx = eg & 7;       // this thread's row-swizzle (j>>2 == eg for m<4)
    const int swn = (w >> 2) & 7;// swizzle of the dst row

    // ---- Phase 2: pair_n + pair_e, 4x4 register tile per thread ----
    float accn[4][4], acce[4][4];
    {
        float bn0[4], be0[4];
        {
            float4 t = *(const float4*)&bnE[f0];
            bn0[0] = t.x; bn0[1] = t.y; bn0[2] = t.z; bn0[3] = t.w;
            t = *(const float4*)&beE[f0];
            be0[0] = t.x; be0[1] = t.y; be0[2] = t.z; be0[3] = t.w;
        }
        // dst-node contribution identical for every edge: hoist into the base.
        for (int c = 0; c < 64; c += 4) {
            const int c4 = c >> 2;
            float4 x  = sn4[(w << 4) | (c4 ^ swn)];
            float4 w0 = *(const float4*)&Wn[(64 + c) * 64 + f0];
            float4 w1 = *(const float4*)&Wn[(65 + c) * 64 + f0];
            float4 w2 = *(const float4*)&Wn[(66 + c) * 64 + f0];
            float4 w3 = *(const float4*)&Wn[(67 + c) * 64 + f0];
            bn0[0] += x.x * w0.x + x.y * w1.x + x.z * w2.x + x.w * w3.x;
            bn0[1] += x.x * w0.y + x.y * w1.y + x.z * w2.y + x.w * w3.y;
            bn0[2] += x.x * w0.z + x.y * w1.z + x.z * w2.z + x.w * w3.z;
            bn0[3] += x.x * w0.w + x.y * w1.w + x.z * w2.w + x.w * w3.w;
        }
#pragma unroll
        for (int m = 0; m < 4; ++m)
#pragma unroll
            for (int ff = 0; ff < 4; ++ff) { accn[m][ff] = bn0[ff]; acce[m][ff] = be0[ff]; }
    }

    for (int c = 0; c < 64; c += 4) {
        const int c4 = c >> 2;
        float wns[4][4], wne[4][4], wes[4][4], wee[4][4];   // [channel q][feature ff]
#pragma unroll
        for (int q = 0; q < 4; ++q) {
            float4 t;
            t = *(const float4*)&Wn[(c + q) * 64 + f0];
            wns[q][0] = t.x; wns[q][1] = t.y; wns[q][2] = t.z; wns[q][3] = t.w;
            t = *(const float4*)&Wn[(128 + c + q) * 64 + f0];
            wne[q][0] = t.x; wne[q][1] = t.y; wne[q][2] = t.z; wne[q][3] = t.w;
            t = *(const float4*)&We[(c + q) * 64 + f0];
            wes[q][0] = t.x; wes[q][1] = t.y; wes[q][2] = t.z; wes[q][3] = t.w;
            t = *(const float4*)&We[(64 + c + q) * 64 + f0];
            wee[q][0] = t.x; wee[q][1] = t.y; wee[q][2] = t.z; wee[q][3] = t.w;
        }
#pragma unroll
        for (int m = 0; m < 4; ++m) {
            const int j = (eg << 2) + m;      // dead rows (j>=w) compute garbage, never stored
            float4 xs = sn4[(j << 4) | (c4 ^ sx)];
            float4 xe = se4[(j << 4) | (c4 ^ sx)];
#pragma unroll
            for (int ff = 0; ff < 4; ++ff) {
                accn[m][ff] += xs.x * wns[0][ff] + xs.y * wns[1][ff] + xs.z * wns[2][ff] + xs.w * wns[3][ff]
                             + xe.x * wne[0][ff] + xe.y * wne[1][ff] + xe.z * wne[2][ff] + xe.w * wne[3][ff];
                acce[m][ff] += xs.x * wes[0][ff] + xs.y * wes[1][ff] + xs.z * wes[2][ff] + xs.w * wes[3][ff]
                             + xe.x * wee[0][ff] + xe.y * wee[1][ff] + xe.z * wee[2][ff] + xe.w * wee[3][ff];
            }
        }
    }

    __syncthreads();   // all phase-2 reads of s_nodes done before pair overlay

    {
        float sn[4] = {0.f, 0.f, 0.f, 0.f};
#pragma unroll
        for (int m = 0; m < 4; ++m) {
            const int j = (eg << 2) + m;
            if (j < w) {
                float4 pe;
                pe.x = fmaxf(acce[m][0], 0.f);
                pe.y = fmaxf(acce[m][1], 0.f);
                pe.z = fmaxf(acce[m][2], 0.f);
                pe.w = fmaxf(acce[m][3], 0.f);
                sn[0] += fmaxf(accn[m][0], 0.f);
                sn[1] += fmaxf(accn[m][1], 0.f);
                sn[2] += fmaxf(accn[m][2], 0.f);
                sn[3] += fmaxf(accn[m][3], 0.f);
                sp4[(j << 4) | (fg ^ sx)] = pe;   // same involution as reads
            }
        }
        *(float4*)&s_red[eg * 64 + f0] = make_float4(sn[0], sn[1], sn[2], sn[3]);
    }
    __syncthreads();

    // ---- half-reduce s_red 16 rows -> 4 rows (each address's only reader is its writer) ----
    {
        const int c = tid & 63, p = tid >> 6;
        float v = s_red[p * 64 + c] + s_red[(p + 4) * 64 + c]
                + s_red[(p + 8) * 64 + c] + s_red[(p + 12) * 64 + c];
        s_red[p * 64 + c] = v;
    }
    __syncthreads();

    // ---- Phase 3 (tid<64, overlapped with everyone's Phase 5 GEMM): out_nodes ----
    if (tid < 64) {
        const int f = tid;
        const float invw = 1.0f / (float)((w > 0) ? w : 1);
        float acc = bias[f];
        for (int c = 0; c < 64; c += 4) {
            const int c4 = c >> 2;
            float4 a0 = *(const float4*)&s_red[c];
            float4 a1 = *(const float4*)&s_red[64 + c];
            float4 a2 = *(const float4*)&s_red[128 + c];
            float4 a3 = *(const float4*)&s_red[192 + c];
            float4 x  = sn4[(w << 4) | (c4 ^ swn)];
            float g0 = (a0.x + a1.x + a2.x + a3.x) * invw;
            float g1 = (a0.y + a1.y + a2.y + a3.y) * invw;
            float g2 = (a0.z + a1.z + a2.z + a3.z) * invw;
            float g3 = (a0.w + a1.w + a2.w + a3.w) * invw;
            acc += g0 * Wnf[(c + 0) * 64 + f] + g1 * Wnf[(c + 1) * 64 + f]
                 + g2 * Wnf[(c + 2) * 64 + f] + g3 * Wnf[(c + 3) * 64 + f]
                 + x.x * Wnf[(64 + c) * 64 + f] + x.y * Wnf[(65 + c) * 64 + f]
                 + x.z * Wnf[(66 + c) * 64 + f] + x.w * Wnf[(67 + c) * 64 + f];
        }
        out[((size_t)b * NN + i) * 64 + f] = fmaxf(acc, 0.f);
    }

    // ---- Phase 5: z = pair_e @ Wef[0:64] (to be scanned), ze = edge @ Wef[64:128] ----
    float zz[4][4], ze[4][4];
#pragma unroll
    for (int m = 0; m < 4; ++m)
#pragma unroll
        for (int ff = 0; ff < 4; ++ff) { zz[m][ff] = 0.f; ze[m][ff] = 0.f; }

    for (int c = 0; c < 64; c += 4) {
        const int c4 = c >> 2;
        float w1[4][4], w2[4][4];
#pragma unroll
        for (int q = 0; q < 4; ++q) {
            float4 t;
            t = *(const float4*)&Wef[(c + q) * 64 + f0];
            w1[q][0] = t.x; w1[q][1] = t.y; w1[q][2] = t.z; w1[q][3] = t.w;
            t = *(const float4*)&Wef[(64 + c + q) * 64 + f0];
            w2[q][0] = t.x; w2[q][1] = t.y; w2[q][2] = t.z; w2[q][3] = t.w;
        }
#pragma unroll
        for (int m = 0; m < 4; ++m) {
            const int j = (eg << 2) + m;
            float4 xp = sp4[(j << 4) | (c4 ^ sx)];   // garbage (finite or not) for j>=w never reaches a store
            float4 xe = se4[(j << 4) | (c4 ^ sx)];
#pragma unroll
            for (int ff = 0; ff < 4; ++ff) {
                zz[m][ff] += xp.x * w1[0][ff] + xp.y * w1[1][ff] + xp.z * w1[2][ff] + xp.w * w1[3][ff];
                ze[m][ff] += xe.x * w2[0][ff] + xe.y * w2[1][ff] + xe.z * w2[2][ff] + xe.w * w2[3][ff];
            }
        }
    }

    // ---- exclusive prefix of zz over j (registers along m, LDS across eg) ----
    float pref[4][4], tot[4];
#pragma unroll
    for (int ff = 0; ff < 4; ++ff) {
        pref[0][ff] = 0.f;
        pref[1][ff] = zz[0][ff];
        pref[2][ff] = pref[1][ff] + zz[1][ff];
        pref[3][ff] = pref[2][ff] + zz[2][ff];
        tot[ff]     = pref[3][ff] + zz[3][ff];
    }
    __syncthreads();                       // phase-3 done reading s_red
    *(float4*)&s_red[eg * 64 + f0] = make_float4(tot[0], tot[1], tot[2], tot[3]);
    __syncthreads();
    float run[4] = {0.f, 0.f, 0.f, 0.f};
    for (int e = 0; e < eg; ++e) {
        float4 t = *(const float4*)&s_red[e * 64 + f0];
        run[0] += t.x; run[1] += t.y; run[2] += t.z; run[3] += t.w;
    }
    // run only sums groups strictly below eg; groups containing/above the w
    // boundary only feed outputs with j>=w, which are never stored.

    // ---- out_edges = relu(prefix_z/max(j,1) + edge@W2 + bias), float4 stores ----
    {
        float4 bv = *(const float4*)&bias[f0];
        float* oute = out + (size_t)BB * NN * 64;  // out_nodes first, then out_edges
#pragma unroll
        for (int m = 0; m < 4; ++m) {
            const int j = (eg << 2) + m;
            if (j < w) {
                const float invj = 1.0f / (float)((j > 0) ? j : 1);
                float4 o;
                o.x = fmaxf((run[0] + pref[m][0]) * invj + ze[m][0] + bv.x, 0.f);
                o.y = fmaxf((run[1] + pref[m][1]) * invj + ze[m][1] + bv.y, 0.f);
                o.z = fmaxf((run[2] + pref[m][2]) * invj + ze[m][2] + bv.z, 0.f);
                o.w = fmaxf((run[3] + pref[m][3]) * invj + ze[m][3] + bv.w, 0.f);
                *(float4*)&oute[((size_t)b * EE + ns + j) * 64 + f0] = o;
            }
        }
    }
}

extern "C" void kernel_launch(void* const* d_in, const int* in_sizes, int n_in,
                              void* d_out, int out_size, void* d_ws, size_t ws_size,
                              hipStream_t stream) {
    const float* nodes = (const float*)d_in[0];
    const float* edges = (const float*)d_in[1];
    const float* Wn1  = (const float*)d_in[2];
    const float* bn1  = (const float*)d_in[3];
    const float* Wn2  = (const float*)d_in[4];
    const float* bn2  = (const float*)d_in[5];
    const float* We1  = (const float*)d_in[6];
    const float* be1  = (const float*)d_in[7];
    const float* We2  = (const float*)d_in[8];
    const float* be2  = (const float*)d_in[9];
    const float* Wnod = (const float*)d_in[10];
    const float* Wedg = (const float*)d_in[11];
    const float* bias = (const float*)d_in[12];
    float* ws = (float*)d_ws;
    float* out = (float*)d_out;

    hipLaunchKernelGGL(eff_weights_kernel, dim3((WS_TOTAL + 255) / 256), dim3(256), 0, stream,
                       Wn1, bn1, Wn2, bn2, We1, be1, We2, be2, ws);
    hipLaunchKernelGGL(main_kernel, dim3(BB * NN), dim3(256), 0, stream,
                       nodes, edges, ws, Wnod, Wedg, bias, out);
}

// Round 3
// 358.956 us; speedup vs baseline: 2.1053x; 1.8515x over previous
//
#include <hip/hip_runtime.h>

// Problem constants (static in the reference)
#define NN 1024
#define MM 64
#define BB 8
#define EE 63456   // sum_i min(i,64) = 2016 + 960*64

// ws float layout
#define WS_WN    0        // Wn_eff  192*64 fp32
#define WS_WE    12288    // We_eff  128*64 fp32
#define WS_BN    20480    // bn_eff  64 fp32
#define WS_BE    20544    // be_eff  64 fp32
#define WS_B2H   20608    // B2 hi: [4 nt][8 ks][64 lane][8 e] ushort = 16384 us = 8192 f
#define WS_B2L   28800    // B2 lo
#define WS_B5H   36992    // B5 hi: [2 nt][8 ks][64 lane][8 e] ushort = 8192 us = 4096 f
#define WS_B5L   41088    // B5 lo
#define WS_TOTAL 45184    // floats (~181 KB)

using short8 = __attribute__((ext_vector_type(8))) short;
using f32x16 = __attribute__((ext_vector_type(16))) float;

__device__ __forceinline__ unsigned bf16_rne(float x) {
    unsigned u = __float_as_uint(x);
    return (u + 0x7fffu + ((u >> 16) & 1u)) >> 16;
}

// Kernel A: collapse the inner linear pairs (no inner ReLU in the reference!)
__global__ void eff_weights_kernel(
    const float* __restrict__ Wn1, const float* __restrict__ bn1,
    const float* __restrict__ Wn2, const float* __restrict__ bn2,
    const float* __restrict__ We1, const float* __restrict__ be1,
    const float* __restrict__ We2, const float* __restrict__ be2,
    float* __restrict__ ws)
{
    int idx = blockIdx.x * 256 + threadIdx.x;
    if (idx < 12288) {                       // Wn_eff (192x64)
        int r = idx >> 6, j = idx & 63;
        float acc = 0.f;
        for (int t = 0; t < 128; ++t) acc += Wn1[r * 128 + t] * Wn2[t * 64 + j];
        ws[WS_WN + idx] = acc;
    } else if (idx < 20480) {                // We_eff (128x64)
        int k = idx - 12288; int r = k >> 6, j = k & 63;
        float acc = 0.f;
        for (int t = 0; t < 128; ++t) acc += We1[r * 128 + t] * We2[t * 64 + j];
        ws[idx] = acc;
    } else if (idx < 20544) {                // bn_eff
        int j = idx - 20480;
        float acc = bn2[j];
        for (int t = 0; t < 128; ++t) acc += bn1[t] * Wn2[t * 64 + j];
        ws[idx] = acc;
    } else if (idx < WS_TOTAL && idx < 20608) { // be_eff
        int j = idx - 20544;
        float acc = be2[j];
        for (int t = 0; t < 128; ++t) acc += be1[t] * We2[t * 64 + j];
        ws[idx] = acc;
    }
}

// Kernel A2: split-bf16 + pack B matrices into MFMA B-fragment order.
// B-fragment (32x32x16): lane l holds n = nt*32+(l&31), k = ks*16+(l>>5)*8+e.
// B2 (K=128: [src;edge] ch, N=128: [accn f | acce f]); B5 = Wef (K=128, N=64).
__global__ void pack_b_kernel(const float* __restrict__ Wef, float* __restrict__ ws)
{
    int idx = blockIdx.x * 256 + threadIdx.x;
    if (idx >= 24576) return;
    float v; int pos, offh, offl;
    if (idx < 16384) {
        int e = idx & 7, l = (idx >> 3) & 63, ks = (idx >> 9) & 7, nt = idx >> 12;
        int k = ks * 16 + (l >> 5) * 8 + e;
        int n = nt * 32 + (l & 31);
        if (n < 64) {
            int r = (k < 64) ? k : (64 + k);        // Wn_eff: src rows 0..63, edge rows 128..191
            v = ws[WS_WN + r * 64 + n];
        } else {
            v = ws[WS_WE + k * 64 + (n - 64)];      // We_eff: src rows 0..63, edge rows 64..127
        }
        pos = idx; offh = WS_B2H; offl = WS_B2L;
    } else {
        int t = idx - 16384;
        int e = t & 7, l = (t >> 3) & 63, ks = (t >> 9) & 7, nt = t >> 12;
        int k = ks * 16 + (l >> 5) * 8 + e;
        int n = nt * 32 + (l & 31);
        v = Wef[k * 64 + n];
        pos = t; offh = WS_B5H; offl = WS_B5L;
    }
    unsigned hh = bf16_rne(v);
    float hf = __uint_as_float(hh << 16);
    unsigned ll = bf16_rne(v - hf);
    ((unsigned short*)(ws + offh))[pos] = (unsigned short)hh;
    ((unsigned short*)(ws + offl))[pos] = (unsigned short)ll;
}

// Kernel B: one block per (batch b, node i). Split-bf16 MFMA 32x32x16.
// A (64 edges x 128 ch: [src||edge]) staged as hi/lo bf16 in LDS, 16B units
// XOR-swizzled (u ^ (row&15)) -> conflict-free fragment reads.
// Phase2: A@B2 -> [accn|acce] (4 waves = 4 N-slabs, 2 M-tiles each, 3-term split).
// pair_e = relu(acce+be) overwrites A's src half; phase5: zz=pair@Wef[0:64],
// ze=edge@Wef[64:128]; exclusive prefix of zz done post-GEMM (linearity).
__global__ __launch_bounds__(256, 4)
void main_kernel(const float* __restrict__ nodes,
                 const float* __restrict__ edges,
                 const float* __restrict__ ws,
                 const float* __restrict__ Wnf,   // W_nodes (128x64) fp32
                 const float* __restrict__ bias,  // bias_edges (64) — both outputs use it
                 float* __restrict__ out)
{
    __shared__ __align__(16) unsigned short s_Ah[64 * 128];  // 16 KB
    __shared__ __align__(16) unsigned short s_Al[64 * 128];  // 16 KB
    __shared__ float s_red[4 * 64];
    __shared__ float s_dd[64];
    __shared__ float s_agg[64];
    __shared__ float s_dst[64];

    const int tid = threadIdx.x;
    const int bx  = blockIdx.x;
    const int b   = bx >> 10;
    const int i   = bx & 1023;
    const int w   = (i < MM) ? i : MM;
    const long ns = (i <= 64) ? ((long)i * (i - 1)) / 2 : 2016L + (long)(i - 64) * 64;

    // ---- Phase 1: stage A = [src||edge] as split bf16 (swizzled), dst row fp32 ----
    if (tid < 16) {
        float4 t = ((const float4*)(nodes + ((size_t)b * NN + i) * 64))[tid];
        *(float4*)&s_dst[tid * 4] = t;
    }
    for (int idx = tid; idx < w * 16; idx += 256) {
        const int row = idx >> 4, q = idx & 15;   // q<8: src unit q ; q>=8: edge unit q-8
        const float* src = (q < 8)
            ? (nodes + ((size_t)b * NN + (i - w) + row) * 64 + q * 8)
            : (edges + ((size_t)b * EE + ns + row) * 64 + (q - 8) * 8);
        float4 x0 = *(const float4*)src;
        float4 x1 = *(const float4*)(src + 4);
        float xv[8] = {x0.x, x0.y, x0.z, x0.w, x1.x, x1.y, x1.z, x1.w};
        unsigned h[8], l2[8];
#pragma unroll
        for (int e = 0; e < 8; ++e) {
            h[e] = bf16_rne(xv[e]);
            float hf = __uint_as_float(h[e] << 16);
            l2[e] = bf16_rne(xv[e] - hf);
        }
        const int u = q ^ (row & 15);
        uint4 H, L;
        H.x = h[0] | (h[1] << 16);  H.y = h[2] | (h[3] << 16);
        H.z = h[4] | (h[5] << 16);  H.w = h[6] | (h[7] << 16);
        L.x = l2[0] | (l2[1] << 16); L.y = l2[2] | (l2[3] << 16);
        L.z = l2[4] | (l2[5] << 16); L.w = l2[6] | (l2[7] << 16);
        *(uint4*)&s_Ah[row * 128 + u * 8] = H;
        *(uint4*)&s_Al[row * 128 + u * 8] = L;
    }
    __syncthreads();

    // ---- ddn[f] = bn_eff[f] + dst . Wn_eff[64..127][f]  (rank-1 hoist) ----
    {
        const int f = tid & 63, p = tid >> 6;
        const float* Wrow = ws + WS_WN + (64 + p * 16) * 64 + f;
        float acc = 0.f;
#pragma unroll
        for (int c = 0; c < 16; ++c) acc += s_dst[p * 16 + c] * Wrow[c * 64];
        s_red[p * 64 + f] = acc;
    }
    __syncthreads();
    if (tid < 64)
        s_dd[tid] = ws[WS_BN + tid] + s_red[tid] + s_red[64 + tid] + s_red[128 + tid] + s_red[192 + tid];

    const int wv  = tid >> 6;
    const int l   = tid & 63;
    const int lo5 = l & 31;
    const int hi  = l >> 5;

    // ---- Phase 2: C = A @ B2, wave wv owns N-slab wv*32, M-tiles 0 and 1 ----
    f32x16 acc0 = {}, acc1 = {};
    {
        const unsigned short* B2h = (const unsigned short*)(ws + WS_B2H);
        const unsigned short* B2l = (const unsigned short*)(ws + WS_B2L);
        const int r0 = lo5, r1 = 32 + lo5;
#pragma unroll
        for (int ks = 0; ks < 8; ++ks) {
            short8 bh = *(const short8*)&B2h[((wv * 8 + ks) * 64 + l) * 8];
            short8 bl = *(const short8*)&B2l[((wv * 8 + ks) * 64 + l) * 8];
            const int u = ks * 2 + hi;
            {
                const int a = r0 * 128 + (u ^ (r0 & 15)) * 8;
                short8 ah = *(const short8*)&s_Ah[a];
                short8 al = *(const short8*)&s_Al[a];
                acc0 = __builtin_amdgcn_mfma_f32_32x32x16_bf16(al, bh, acc0, 0, 0, 0);
                acc0 = __builtin_amdgcn_mfma_f32_32x32x16_bf16(ah, bl, acc0, 0, 0, 0);
                acc0 = __builtin_amdgcn_mfma_f32_32x32x16_bf16(ah, bh, acc0, 0, 0, 0);
            }
            {
                const int a = r1 * 128 + (u ^ (r1 & 15)) * 8;
                short8 ah = *(const short8*)&s_Ah[a];
                short8 al = *(const short8*)&s_Al[a];
                acc1 = __builtin_amdgcn_mfma_f32_32x32x16_bf16(al, bh, acc1, 0, 0, 0);
                acc1 = __builtin_amdgcn_mfma_f32_32x32x16_bf16(ah, bl, acc1, 0, 0, 0);
                acc1 = __builtin_amdgcn_mfma_f32_32x32x16_bf16(ah, bh, acc1, 0, 0, 0);
            }
        }
    }
    __syncthreads();   // phase-2 A reads complete before pair overwrites A

    if (wv < 2) {
        // accn reduce: agg[f] = sum_{j<w} relu(C + ddn[f])
        const int f = wv * 32 + lo5;
        const float dd = s_dd[f];
        float sum = 0.f;
#pragma unroll
        for (int reg = 0; reg < 16; ++reg) {
            const int r = (reg & 3) + 8 * (reg >> 2) + 4 * hi;
            if (r < w)      sum += fmaxf(acc0[reg] + dd, 0.f);
            if (32 + r < w) sum += fmaxf(acc1[reg] + dd, 0.f);
        }
        sum += __shfl_xor(sum, 32);
        if (hi == 0) s_agg[f] = sum;
    } else {
        // pair_e = relu(C + be) -> split bf16 -> overwrite A src half (k = f)
        const int f = (wv - 2) * 32 + lo5;
        const float be = ws[WS_BE + f];
        const int uq = f >> 3, fo = f & 7;
#pragma unroll
        for (int reg = 0; reg < 16; ++reg) {
            const int r = (reg & 3) + 8 * (reg >> 2) + 4 * hi;
            {
                float p = (r < w) ? fmaxf(acc0[reg] + be, 0.f) : 0.f;
                unsigned hh = bf16_rne(p);
                unsigned ll = bf16_rne(p - __uint_as_float(hh << 16));
                const int a = r * 128 + (uq ^ (r & 15)) * 8 + fo;
                s_Ah[a] = (unsigned short)hh;
                s_Al[a] = (unsigned short)ll;
            }
            {
                const int r2 = 32 + r;
                float p = (r2 < w) ? fmaxf(acc1[reg] + be, 0.f) : 0.f;
                unsigned hh = bf16_rne(p);
                unsigned ll = bf16_rne(p - __uint_as_float(hh << 16));
                const int a = r2 * 128 + (uq ^ (r2 & 15)) * 8 + fo;
                s_Ah[a] = (unsigned short)hh;
                s_Al[a] = (unsigned short)ll;
            }
        }
    }
    __syncthreads();   // pair in LDS; s_agg ready

    // ---- Phase 5: zz = pair @ Wef[0:64] (ks 0..3), ze = edge @ Wef[64:128] (ks 4..7) ----
    const int mt = wv >> 1, ntc = wv & 1;
    const int row = mt * 32 + lo5;
    f32x16 zz = {}, ze = {};
    {
        const unsigned short* B5h = (const unsigned short*)(ws + WS_B5H);
        const unsigned short* B5l = (const unsigned short*)(ws + WS_B5L);
#pragma unroll
        for (int ks = 0; ks < 8; ++ks) {
            short8 bh = *(const short8*)&B5h[((ntc * 8 + ks) * 64 + l) * 8];
            short8 bl = *(const short8*)&B5l[((ntc * 8 + ks) * 64 + l) * 8];
            const int a = row * 128 + ((ks * 2 + hi) ^ (row & 15)) * 8;
            short8 ah = *(const short8*)&s_Ah[a];
            short8 al = *(const short8*)&s_Al[a];
            if (ks < 4) {
                zz = __builtin_amdgcn_mfma_f32_32x32x16_bf16(al, bh, zz, 0, 0, 0);
                zz = __builtin_amdgcn_mfma_f32_32x32x16_bf16(ah, bl, zz, 0, 0, 0);
                zz = __builtin_amdgcn_mfma_f32_32x32x16_bf16(ah, bh, zz, 0, 0, 0);
            } else {
                ze = __builtin_amdgcn_mfma_f32_32x32x16_bf16(al, bh, ze, 0, 0, 0);
                ze = __builtin_amdgcn_mfma_f32_32x32x16_bf16(ah, bl, ze, 0, 0, 0);
                ze = __builtin_amdgcn_mfma_f32_32x32x16_bf16(ah, bh, ze, 0, 0, 0);
            }
        }
    }

    // ---- exclusive prefix of zz over rows (per column): in-lane + hi-exchange + cross-mt ----
    float pz[16], G[4];
#pragma unroll
    for (int g = 0; g < 4; ++g) {
        float a0 = zz[g * 4 + 0], a1 = zz[g * 4 + 1], a2 = zz[g * 4 + 2], a3 = zz[g * 4 + 3];
        pz[g * 4 + 0] = 0.f;
        pz[g * 4 + 1] = a0;
        pz[g * 4 + 2] = a0 + a1;
        pz[g * 4 + 3] = a0 + a1 + a2;
        G[g] = a0 + a1 + a2 + a3;
    }
    float Gp[4];
#pragma unroll
    for (int g = 0; g < 4; ++g) Gp[g] = __shfl_xor(G[g], 32);
    float run = 0.f, base[4];
#pragma unroll
    for (int g = 0; g < 4; ++g) {
        const float g0 = hi ? Gp[g] : G[g];        // h=0 group sum
        base[g] = run + (hi ? g0 : 0.f);
        run += G[g] + Gp[g];
    }
    // run = total over this mt-block's 32 rows (this column)
    if (mt == 0 && hi == 0) s_red[ntc * 32 + lo5] = run;
    __syncthreads();
    const float cbase = (mt == 1) ? s_red[ntc * 32 + lo5] : 0.f;

    // ---- out_edges = relu(prefix/max(j,1) + ze + bias) ----
    {
        const int f = ntc * 32 + lo5;
        const float bv = bias[f];
        float* oute = out + (size_t)BB * NN * 64;
#pragma unroll
        for (int reg = 0; reg < 16; ++reg) {
            const int g = reg >> 2;
            const int r = (reg & 3) + 8 * g + 4 * hi;
            const int j = mt * 32 + r;
            if (j < w) {
                const float pref = cbase + base[g] + pz[reg];
                const float invj = (j > 0) ? (1.f / (float)j) : 1.f;
                oute[((size_t)b * EE + ns + j) * 64 + f] = fmaxf(pref * invj + ze[reg] + bv, 0.f);
            }
        }
    }

    // ---- out_nodes (tid<64, fp32 GEMV): [agg/w || dst] @ W_nodes + bias ----
    if (tid < 64) {
        const int f = tid;
        const float invw = 1.0f / (float)((w > 0) ? w : 1);
        float acc = bias[f];
        for (int c = 0; c < 64; ++c)
            acc += (s_agg[c] * invw) * Wnf[c * 64 + f] + s_dst[c] * Wnf[(64 + c) * 64 + f];
        out[((size_t)b * NN + i) * 64 + f] = fmaxf(acc, 0.f);
    }
}

extern "C" void kernel_launch(void* const* d_in, const int* in_sizes, int n_in,
                              void* d_out, int out_size, void* d_ws, size_t ws_size,
                              hipStream_t stream) {
    const float* nodes = (const float*)d_in[0];
    const float* edges = (const float*)d_in[1];
    const float* Wn1  = (const float*)d_in[2];
    const float* bn1  = (const float*)d_in[3];
    const float* Wn2  = (const float*)d_in[4];
    const float* bn2  = (const float*)d_in[5];
    const float* We1  = (const float*)d_in[6];
    const float* be1  = (const float*)d_in[7];
    const float* We2  = (const float*)d_in[8];
    const float* be2  = (const float*)d_in[9];
    const float* Wnod = (const float*)d_in[10];
    const float* Wedg = (const float*)d_in[11];
    const float* bias = (const float*)d_in[12];
    float* ws = (float*)d_ws;
    float* out = (float*)d_out;

    hipLaunchKernelGGL(eff_weights_kernel, dim3((20608 + 255) / 256), dim3(256), 0, stream,
                       Wn1, bn1, Wn2, bn2, We1, be1, We2, be2, ws);
    hipLaunchKernelGGL(pack_b_kernel, dim3(96), dim3(256), 0, stream, Wedg, ws);
    hipLaunchKernelGGL(main_kernel, dim3(BB * NN), dim3(256), 0, stream,
                       nodes, edges, ws, Wnod, bias, out);
}